// Round 1
// baseline (591.360 us; speedup 1.0000x reference)
//
#include <hip/hip_runtime.h>
#include <math.h>

// Problem constants
#define NB    16384   // batch
#define DIN   512     // dense in
#define NSP   26      // sparse embeddings
#define EMBD  128     // embedding dim
#define NOUT  512     // output dim
#define NI_   27      // NSP + 1
#define NTRI  378     // NI*(NI+1)/2
#define DOTK  890     // NTRI + DIN
#define KPAD  896     // DOTK padded to multiple of 32
#define TSTR  132     // LDS row stride for T (128 + 4 pad, breaks bank aliasing)

// ---------------------------------------------------------------------------
// Pad Wo (512 x 890) into ws as (512 x 896), zero-filling the 6 pad columns.
// ws is re-poisoned to 0xAA before every launch, so this must run every call.
// ---------------------------------------------------------------------------
__global__ __launch_bounds__(256) void pad_wo_k(const float* __restrict__ wo,
                                                float* __restrict__ wop) {
    int idx = blockIdx.x * 256 + threadIdx.x;
    if (idx >= NOUT * KPAD) return;
    int o = idx / KPAD;
    int k = idx - o * KPAD;
    wop[idx] = (k < DOTK) ? wo[o * DOTK + k] : 0.0f;
}

// ---------------------------------------------------------------------------
// Generic fp32 NT-GEMM: C[M x N] = A[M x lda] dot-rows B[N x ldb] + bias[N].
// Both operands are K-contiguous (row-major with K inner) -> pure dot products.
// 64x64 tile per 256-thread block, K-chunk 32, 4x4 micro-tile per thread.
// LDS stored transposed (As[k][m]) so the inner loop uses aligned float4 reads.
// Store mapping (row = tid&31, kf = (tid>>5)*4) keeps LDS writes at <=2-way
// bank conflicts (free per m136).
// Requires: M%64==0, N%64==0, K%32==0.
// grid = (N/64, M/64), block = 256.
// ---------------------------------------------------------------------------
__global__ __launch_bounds__(256) void gemm_nt64(const float* __restrict__ A, int lda,
                                                 const float* __restrict__ Bm, int ldb,
                                                 const float* __restrict__ bias,
                                                 float* __restrict__ C, int ldc, int K) {
    __shared__ float As[32 * 64];
    __shared__ float Bs[32 * 64];

    const int tid = threadIdx.x;
    const int tx  = tid & 15;   // n-index group
    const int ty  = tid >> 4;   // m-index group
    const int m0  = blockIdx.y * 64;
    const int n0  = blockIdx.x * 64;

    const int row = tid & 31;        // tile row for staging loads
    const int kf  = (tid >> 5) * 4;  // k offset 0,4,...,28

    const float* Ap0 = A + (size_t)(m0 + row)      * lda + kf;
    const float* Ap1 = A + (size_t)(m0 + row + 32) * lda + kf;
    const float* Bp0 = Bm + (size_t)(n0 + row)      * ldb + kf;
    const float* Bp1 = Bm + (size_t)(n0 + row + 32) * ldb + kf;

    float acc[4][4] = {};

    for (int kb = 0; kb < K; kb += 32) {
        float4 a0 = *(const float4*)(Ap0 + kb);
        float4 a1 = *(const float4*)(Ap1 + kb);
        float4 b0 = *(const float4*)(Bp0 + kb);
        float4 b1 = *(const float4*)(Bp1 + kb);
        __syncthreads();  // previous iteration's LDS reads must finish
        As[(kf + 0) * 64 + row]      = a0.x;
        As[(kf + 1) * 64 + row]      = a0.y;
        As[(kf + 2) * 64 + row]      = a0.z;
        As[(kf + 3) * 64 + row]      = a0.w;
        As[(kf + 0) * 64 + row + 32] = a1.x;
        As[(kf + 1) * 64 + row + 32] = a1.y;
        As[(kf + 2) * 64 + row + 32] = a1.z;
        As[(kf + 3) * 64 + row + 32] = a1.w;
        Bs[(kf + 0) * 64 + row]      = b0.x;
        Bs[(kf + 1) * 64 + row]      = b0.y;
        Bs[(kf + 2) * 64 + row]      = b0.z;
        Bs[(kf + 3) * 64 + row]      = b0.w;
        Bs[(kf + 0) * 64 + row + 32] = b1.x;
        Bs[(kf + 1) * 64 + row + 32] = b1.y;
        Bs[(kf + 2) * 64 + row + 32] = b1.z;
        Bs[(kf + 3) * 64 + row + 32] = b1.w;
        __syncthreads();
#pragma unroll
        for (int kk = 0; kk < 32; ++kk) {
            float av[4], bv[4];
            *(float4*)av = *(const float4*)&As[kk * 64 + ty * 4];
            *(float4*)bv = *(const float4*)&Bs[kk * 64 + tx * 4];
#pragma unroll
            for (int i = 0; i < 4; ++i)
#pragma unroll
                for (int j = 0; j < 4; ++j)
                    acc[i][j] += av[i] * bv[j];
        }
    }

    float bb[4];
#pragma unroll
    for (int j = 0; j < 4; ++j) bb[j] = bias[n0 + tx * 4 + j];
#pragma unroll
    for (int i = 0; i < 4; ++i) {
        float o4[4];
#pragma unroll
        for (int j = 0; j < 4; ++j) o4[j] = acc[i][j] + bb[j];
        *(float4*)(C + (size_t)(m0 + ty * 4 + i) * ldc + n0 + tx * 4) = *(const float4*)o4;
    }
}

// ---------------------------------------------------------------------------
// Interaction: one block per batch row.
// T = [dense_proj_row ; sparse_row]  (27 x 128) staged in LDS (stride 132).
// Writes Zflat row = [dense_row(512) | tril(T T^T)(378) | zeros(6)] (stride 896).
// ---------------------------------------------------------------------------
__global__ __launch_bounds__(256) void interact_k(const float* __restrict__ dense,
                                                  const float* __restrict__ dproj,
                                                  const float* __restrict__ sparse,
                                                  float* __restrict__ zf) {
    __shared__ float T[NI_ * TSTR];
    const int b   = blockIdx.x;
    const int tid = threadIdx.x;

    // dense_proj row -> T[0]
    if (tid < 32) {
        float4 v = *(const float4*)(dproj + (size_t)b * EMBD + tid * 4);
        *(float4*)&T[tid * 4] = v;
    }
    // sparse row (26*128 = 832 float4) -> T[1..26]
    for (int p = tid; p < 832; p += 256) {
        int e  = p >> 5;   // embedding index
        int k4 = p & 31;   // float4 index within embedding
        float4 v = *(const float4*)(sparse + (size_t)b * (NSP * EMBD) + p * 4);
        *(float4*)&T[(1 + e) * TSTR + k4 * 4] = v;
    }
    // dense passthrough -> zf[0:512]; zero the 6 pad columns (ws is poisoned)
    float* zrow = zf + (size_t)b * KPAD;
    if (tid < 128) {
        float4 v = *(const float4*)(dense + (size_t)b * DIN + tid * 4);
        *(float4*)(zrow + tid * 4) = v;
    }
    if (tid < KPAD - DOTK) zrow[DOTK + tid] = 0.0f;
    __syncthreads();

    // 378 lower-triangular dot products, row-major tril order: p = i(i+1)/2 + j
    for (int p = tid; p < NTRI; p += 256) {
        int i = (int)((sqrtf(8.0f * (float)p + 1.0f) - 1.0f) * 0.5f);
        while ((i + 1) * (i + 2) / 2 <= p) ++i;
        while (i * (i + 1) / 2 > p) --i;
        int j = p - i * (i + 1) / 2;
        const float* ti = &T[i * TSTR];
        const float* tj = &T[j * TSTR];
        float s = 0.0f;
#pragma unroll
        for (int k4 = 0; k4 < 32; ++k4) {
            float4 a = *(const float4*)(ti + k4 * 4);
            float4 c = *(const float4*)(tj + k4 * 4);
            s += a.x * c.x + a.y * c.y + a.z * c.z + a.w * c.w;
        }
        zrow[DIN + p] = s;
    }
}

// ---------------------------------------------------------------------------
extern "C" void kernel_launch(void* const* d_in, const int* in_sizes, int n_in,
                              void* d_out, int out_size, void* d_ws, size_t ws_size,
                              hipStream_t stream) {
    const float* dense  = (const float*)d_in[0];  // (16384, 512)
    const float* sparse = (const float*)d_in[1];  // (16384, 26, 128)
    const float* Wp     = (const float*)d_in[2];  // (128, 512)
    const float* bp     = (const float*)d_in[3];  // (128,)
    const float* Wo     = (const float*)d_in[4];  // (512, 890)
    const float* bo     = (const float*)d_in[5];  // (512,)
    float* out = (float*)d_out;                   // (16384, 512)

    float* ws    = (float*)d_ws;
    float* dproj = ws;                                       // 16384*128 floats
    float* zf    = dproj + (size_t)NB * EMBD;                // 16384*896 floats
    float* wop   = zf + (size_t)NB * KPAD;                   // 512*896 floats

    // 1) pad Wo into (512 x 896)
    pad_wo_k<<<(NOUT * KPAD + 255) / 256, 256, 0, stream>>>(Wo, wop);

    // 2) dense_proj = dense @ Wp.T + bp   : M=16384, N=128, K=512
    gemm_nt64<<<dim3(EMBD / 64, NB / 64), 256, 0, stream>>>(
        dense, DIN, Wp, DIN, bp, dproj, EMBD, DIN);

    // 3) build Zflat rows (dense | tril(T T^T) | pad)
    interact_k<<<NB, 256, 0, stream>>>(dense, dproj, sparse, zf);

    // 4) out = Zflat @ WoPad.T + bo       : M=16384, N=512, K=896
    gemm_nt64<<<dim3(NOUT / 64, NB / 64), 256, 0, stream>>>(
        zf, KPAD, wop, KPAD, bo, out, NOUT, KPAD);
}

// Round 2
// 436.078 us; speedup vs baseline: 1.3561x; 1.3561x over previous
//
#include <hip/hip_runtime.h>

// Problem constants
#define NB    16384   // batch
#define DIN   512     // dense in
#define NSP   26      // sparse embeddings
#define EMBD  128     // embedding dim
#define NOUT  512     // output dim
#define NI_   27      // NSP + 1
#define NTRI  378     // NI*(NI+1)/2
#define DOTK  890     // NTRI + DIN
#define KPAD  896     // DOTK padded to multiple of 32

typedef __attribute__((ext_vector_type(8)))  short bf16x8;  // 8 bf16 = 4 VGPRs
typedef __attribute__((ext_vector_type(4)))  float f32x4;   // MFMA 16x16 acc

// fp32 -> bf16 (RNE), bit-level
__device__ __forceinline__ short f2bf(float f) {
    unsigned u = __builtin_bit_cast(unsigned, f);
    unsigned r = (u + 0x7FFFu + ((u >> 16) & 1u)) >> 16;
    return (short)r;
}

__device__ __forceinline__ bf16x8 cvt8(float4 a, float4 b) {
    bf16x8 r;
    r[0] = f2bf(a.x); r[1] = f2bf(a.y); r[2] = f2bf(a.z); r[3] = f2bf(a.w);
    r[4] = f2bf(b.x); r[5] = f2bf(b.y); r[6] = f2bf(b.z); r[7] = f2bf(b.w);
    return r;
}

// ---------------------------------------------------------------------------
// Weights prep: wop = bf16 pad(Wo) (512 x 896, zero pad cols), wpb = bf16 Wp.
// ws is re-poisoned each launch -> must run every call.
// ---------------------------------------------------------------------------
__global__ __launch_bounds__(256) void prep_w_k(const float* __restrict__ Wo,
                                                const float* __restrict__ Wp,
                                                short* __restrict__ wop,
                                                short* __restrict__ wpb) {
    int idx = blockIdx.x * 256 + threadIdx.x;
    if (idx < NOUT * KPAD) {
        int o = idx / KPAD, k = idx - o * KPAD;
        wop[idx] = (k < DOTK) ? f2bf(Wo[o * DOTK + k]) : (short)0;
    } else {
        int j = idx - NOUT * KPAD;
        if (j < EMBD * DIN) wpb[j] = f2bf(Wp[j]);
    }
}

// ---------------------------------------------------------------------------
// dense fp32 -> bf16 into zfb[:, 0:512] (row stride 896)
// ---------------------------------------------------------------------------
__global__ __launch_bounds__(256) void conv_dense_k(const float* __restrict__ dense,
                                                    short* __restrict__ zfb) {
    int idx = blockIdx.x * 256 + threadIdx.x;   // NB*128 float4 groups
    int b = idx >> 7, c = (idx & 127) * 4;
    float4 v = *(const float4*)(dense + (size_t)b * DIN + c);
    unsigned lo = ((unsigned)(unsigned short)f2bf(v.y) << 16) | (unsigned short)f2bf(v.x);
    unsigned hi = ((unsigned)(unsigned short)f2bf(v.w) << 16) | (unsigned short)f2bf(v.z);
    int2 pk; pk.x = (int)lo; pk.y = (int)hi;
    *(int2*)(zfb + (size_t)b * KPAD + c) = pk;
}

// ---------------------------------------------------------------------------
// bf16 NT-GEMM via MFMA 16x16x32: C[M x N] = A[M x lda] . rows(B[N x ldb]) + bias
// Block: 256 threads = 4 waves in 2x2, each wave (BM/2 x BN/2).
// K-chunk 32; LDS rows padded to 40 bf16 (80 B) -> conflict-free b128 phases.
// Requires M%BM==0, N%BN==0, K%32==0, BM,BN in {64,128}. grid=(N/BN, M/BM).
// ---------------------------------------------------------------------------
template <int BM, int BN, bool OUTBF>
__global__ __launch_bounds__(256) void gemm_mfma(const short* __restrict__ A, int lda,
                                                 const short* __restrict__ Bm, int ldb,
                                                 const float* __restrict__ bias,
                                                 void* __restrict__ Cp, int ldc, int K) {
    constexpr int SK = 40;                 // LDS row stride (bf16)
    constexpr int WM = BM / 2, WN = BN / 2;
    constexpr int MT = WM / 16, NT = WN / 16;
    __shared__ short As[BM * SK];
    __shared__ short Bs[BN * SK];

    const int tid = threadIdx.x;
    const int w = tid >> 6, l = tid & 63;
    const int wm = w >> 1, wn = w & 1;
    const int r0 = l & 15, q = l >> 4;
    const int m0 = blockIdx.y * BM, n0 = blockIdx.x * BN;
    const int srow = tid >> 2, sseg = tid & 3;   // staging: 64 rows x 4 16B-segs

    const f32x4 zero4 = {0.f, 0.f, 0.f, 0.f};
    f32x4 acc[MT][NT];
#pragma unroll
    for (int mi = 0; mi < MT; ++mi)
#pragma unroll
        for (int ni = 0; ni < NT; ++ni) acc[mi][ni] = zero4;

    for (int k0 = 0; k0 < K; k0 += 32) {
        int4 ar[BM / 64], br[BN / 64];
#pragma unroll
        for (int i = 0; i < BM / 64; ++i)
            ar[i] = *(const int4*)(A + (size_t)(m0 + srow + i * 64) * lda + k0 + sseg * 8);
#pragma unroll
        for (int i = 0; i < BN / 64; ++i)
            br[i] = *(const int4*)(Bm + (size_t)(n0 + srow + i * 64) * ldb + k0 + sseg * 8);
        __syncthreads();   // prior ds_reads done before overwrite
#pragma unroll
        for (int i = 0; i < BM / 64; ++i)
            *(int4*)&As[(srow + i * 64) * SK + sseg * 8] = ar[i];
#pragma unroll
        for (int i = 0; i < BN / 64; ++i)
            *(int4*)&Bs[(srow + i * 64) * SK + sseg * 8] = br[i];
        __syncthreads();

        bf16x8 af[MT], bfr[NT];
#pragma unroll
        for (int mi = 0; mi < MT; ++mi)
            af[mi] = *(const bf16x8*)&As[(wm * WM + mi * 16 + r0) * SK + q * 8];
#pragma unroll
        for (int ni = 0; ni < NT; ++ni)
            bfr[ni] = *(const bf16x8*)&Bs[(wn * WN + ni * 16 + r0) * SK + q * 8];
#pragma unroll
        for (int mi = 0; mi < MT; ++mi)
#pragma unroll
            for (int ni = 0; ni < NT; ++ni)
                acc[mi][ni] = __builtin_amdgcn_mfma_f32_16x16x32_bf16(
                    af[mi], bfr[ni], acc[mi][ni], 0, 0, 0);
    }

    // epilogue: C/D layout col=lane&15, row=(lane>>4)*4+reg  [m89/m91]
#pragma unroll
    for (int mi = 0; mi < MT; ++mi) {
#pragma unroll
        for (int ni = 0; ni < NT; ++ni) {
            int col = n0 + wn * WN + ni * 16 + r0;
            float bb = bias[col];
#pragma unroll
            for (int r = 0; r < 4; ++r) {
                int row = m0 + wm * WM + mi * 16 + q * 4 + r;
                float v = acc[mi][ni][r] + bb;
                if (OUTBF) ((short*)Cp)[(size_t)row * ldc + col] = f2bf(v);
                else       ((float*)Cp)[(size_t)row * ldc + col] = v;
            }
        }
    }
}

// ---------------------------------------------------------------------------
// Interaction via MFMA: one wave per batch row. T = [dproj ; sparse] (27x128,
// zero-padded to 32). Gram = T.T^T with 16x16x32 MFMA; tril -> zfb[512:890] bf16,
// cols [890:896) zeroed. Skips the col>row tile (acc01 unused by tril).
// ---------------------------------------------------------------------------
__global__ __launch_bounds__(256) void interact_mfma(const float* __restrict__ sparse,
                                                     const short* __restrict__ dprojb,
                                                     short* __restrict__ zfb) {
    __shared__ short zt[4][NTRI];
    const int w = threadIdx.x >> 6, l = threadIdx.x & 63;
    const int b = blockIdx.x * 4 + w;
    const int r0 = l & 15, q = l >> 4;

    const float* srow = sparse + (size_t)b * (NSP * EMBD);
    const short* dp = dprojb + (size_t)b * EMBD;

    const f32x4 zero4 = {0.f, 0.f, 0.f, 0.f};
    f32x4 acc00 = zero4, acc10 = zero4, acc11 = zero4;

#pragma unroll
    for (int kc = 0; kc < 4; ++kc) {
        int k = kc * 32 + q * 8;
        bf16x8 f0, f1;
        if (r0 == 0) {
            f0 = *(const bf16x8*)(dp + k);                  // T row 0 = dense_proj
        } else {
            const float* p = srow + (size_t)(r0 - 1) * EMBD + k;
            f0 = cvt8(*(const float4*)p, *(const float4*)(p + 4));
        }
        if (r0 <= 10) {                                     // T rows 16..26
            const float* p = srow + (size_t)(15 + r0) * EMBD + k;
            f1 = cvt8(*(const float4*)p, *(const float4*)(p + 4));
        } else {
            f1 = (bf16x8){0, 0, 0, 0, 0, 0, 0, 0};
        }
        acc00 = __builtin_amdgcn_mfma_f32_16x16x32_bf16(f0, f0, acc00, 0, 0, 0);
        acc10 = __builtin_amdgcn_mfma_f32_16x16x32_bf16(f1, f0, acc10, 0, 0, 0);
        acc11 = __builtin_amdgcn_mfma_f32_16x16x32_bf16(f1, f1, acc11, 0, 0, 0);
    }

    // scatter tril entries to LDS: row=(mi*16 + q*4 + r), col=(ni*16 + r0)
#pragma unroll
    for (int r = 0; r < 4; ++r) {
        int row, col;
        row = q * 4 + r;       col = r0;                    // tile (0,0)
        if (col <= row)             zt[w][row * (row + 1) / 2 + col] = f2bf(acc00[r]);
        row = 16 + q * 4 + r;  col = r0;                    // tile (1,0)
        if (row < NI_)              zt[w][row * (row + 1) / 2 + col] = f2bf(acc10[r]);
        /* tile (1,1) */       col = 16 + r0;
        if (row < NI_ && col <= row) zt[w][row * (row + 1) / 2 + col] = f2bf(acc11[r]);
    }
    __syncthreads();

    // coalesced copy: 4 rows x (378 tril + 6 zero-pad) bf16
    const int b0 = blockIdx.x * 4;
    for (int idx = threadIdx.x; idx < 4 * 384; idx += 256) {
        int rw = idx / 384, c = idx - rw * 384;
        short v = (c < NTRI) ? zt[rw][c] : (short)0;
        zfb[(size_t)(b0 + rw) * KPAD + DIN + c] = v;
    }
}

// ---------------------------------------------------------------------------
extern "C" void kernel_launch(void* const* d_in, const int* in_sizes, int n_in,
                              void* d_out, int out_size, void* d_ws, size_t ws_size,
                              hipStream_t stream) {
    const float* dense  = (const float*)d_in[0];  // (16384, 512)
    const float* sparse = (const float*)d_in[1];  // (16384, 26, 128)
    const float* Wp     = (const float*)d_in[2];  // (128, 512)
    const float* bp     = (const float*)d_in[3];  // (128,)
    const float* Wo     = (const float*)d_in[4];  // (512, 890)
    const float* bo     = (const float*)d_in[5];  // (512,)
    float* out = (float*)d_out;                   // (16384, 512)

    short* zfb    = (short*)d_ws;                          // NB x 896 bf16
    short* dprojb = zfb + (size_t)NB * KPAD;               // NB x 128 bf16
    short* wop    = dprojb + (size_t)NB * EMBD;            // 512 x 896 bf16
    short* wpb    = wop + (size_t)NOUT * KPAD;             // 128 x 512 bf16

    // 1) weights -> bf16 (Wo padded)
    prep_w_k<<<(NOUT * KPAD + EMBD * DIN + 255) / 256, 256, 0, stream>>>(Wo, Wp, wop, wpb);

    // 2) dense -> bf16 into zfb[:, 0:512]
    conv_dense_k<<<(NB * 128 + 255) / 256, 256, 0, stream>>>(dense, zfb);

    // 3) dproj = dense @ Wp.T + bp  (M=16384, N=128, K=512), bf16 out
    gemm_mfma<128, 64, true><<<dim3(EMBD / 64, NB / 128), 256, 0, stream>>>(
        zfb, KPAD, wpb, DIN, bp, dprojb, EMBD, DIN);

    // 4) per-row Gram -> zfb[:, 512:896]
    interact_mfma<<<NB / 4, 256, 0, stream>>>(sparse, dprojb, zfb);

    // 5) out = Zflat @ Wo.T + bo  (M=16384, N=512, K=896), fp32 out
    gemm_mfma<128, 128, false><<<dim3(NOUT / 128, NB / 128), 256, 0, stream>>>(
        zfb, KPAD, wop, KPAD, bo, out, NOUT, KPAD);
}

// Round 3
// 383.348 us; speedup vs baseline: 1.5426x; 1.1376x over previous
//
#include <hip/hip_runtime.h>

// Problem constants
#define NB    16384   // batch
#define DIN   512     // dense in
#define NSP   26      // sparse embeddings
#define EMBD  128     // embedding dim
#define NOUT  512     // output dim
#define NI_   27      // NSP + 1
#define NTRI  378     // NI*(NI+1)/2
#define DOTK  890     // NTRI + DIN
#define KPAD  896     // DOTK padded to multiple of 32

typedef __attribute__((ext_vector_type(8)))  short bf16x8;  // 8 bf16 = 4 VGPRs
typedef __attribute__((ext_vector_type(4)))  float f32x4;   // MFMA 16x16 acc

// fp32 -> bf16 (RNE), bit-level
__device__ __forceinline__ short f2bf(float f) {
    unsigned u = __builtin_bit_cast(unsigned, f);
    unsigned r = (u + 0x7FFFu + ((u >> 16) & 1u)) >> 16;
    return (short)r;
}

__device__ __forceinline__ bf16x8 cvt8(float4 a, float4 b) {
    bf16x8 r;
    r[0] = f2bf(a.x); r[1] = f2bf(a.y); r[2] = f2bf(a.z); r[3] = f2bf(a.w);
    r[4] = f2bf(b.x); r[5] = f2bf(b.y); r[6] = f2bf(b.z); r[7] = f2bf(b.w);
    return r;
}

// async global -> LDS, 16 B per lane; lds dst is wave-uniform base (+lane*16 by HW)
__device__ __forceinline__ void gld_lds16(const void* g, void* l) {
    __builtin_amdgcn_global_load_lds((const __attribute__((address_space(1))) void*)g,
                                     (__attribute__((address_space(3))) void*)l,
                                     16, 0, 0);
}

// ---------------------------------------------------------------------------
// Weights prep: wop = bf16 pad(Wo) (512 x 896, zero pad cols), wpb = bf16 Wp.
// ws is re-poisoned each launch -> must run every call.
// ---------------------------------------------------------------------------
__global__ __launch_bounds__(256) void prep_w_k(const float* __restrict__ Wo,
                                                const float* __restrict__ Wp,
                                                short* __restrict__ wop,
                                                short* __restrict__ wpb) {
    int idx = blockIdx.x * 256 + threadIdx.x;
    if (idx < NOUT * KPAD) {
        int o = idx / KPAD, k = idx - o * KPAD;
        wop[idx] = (k < DOTK) ? f2bf(Wo[o * DOTK + k]) : (short)0;
    } else {
        int j = idx - NOUT * KPAD;
        if (j < EMBD * DIN) wpb[j] = f2bf(Wp[j]);
    }
}

// ---------------------------------------------------------------------------
// dense fp32 -> bf16 into zfb[:, 0:512] (row stride 896)
// ---------------------------------------------------------------------------
__global__ __launch_bounds__(256) void conv_dense_k(const float* __restrict__ dense,
                                                    short* __restrict__ zfb) {
    int idx = blockIdx.x * 256 + threadIdx.x;   // NB*128 float4 groups
    int b = idx >> 7, c = (idx & 127) * 4;
    float4 v = *(const float4*)(dense + (size_t)b * DIN + c);
    unsigned lo = ((unsigned)(unsigned short)f2bf(v.y) << 16) | (unsigned short)f2bf(v.x);
    unsigned hi = ((unsigned)(unsigned short)f2bf(v.w) << 16) | (unsigned short)f2bf(v.z);
    int2 pk; pk.x = (int)lo; pk.y = (int)hi;
    *(int2*)(zfb + (size_t)b * KPAD + c) = pk;
}

// ---------------------------------------------------------------------------
// bf16 NT-GEMM via MFMA 16x16x32: C[M x N] = A[M x lda] . rows(B[N x ldb]) + bias
// Block: 256 threads = 4 waves in 2x2, each wave (BM/2 x BN/2).
// Staging: global_load_lds width=16 (m97 pattern). LDS unpadded (32 shorts/row),
// XOR-swizzled: physical 16B-seg = logical seg ^ ((row>>1)&3). In any 8-lane
// b128 read phase banks = 16*(row&1) + 4*(q^key) -> all distinct, conflict-free.
// Requires M%BM==0, N%BN==0, K%32==0, BM,BN in {64,128}. grid=(N/BN, M/BM).
// ---------------------------------------------------------------------------
template <int BM, int BN, bool OUTBF>
__global__ __launch_bounds__(256) void gemm_mfma(const short* __restrict__ A, int lda,
                                                 const short* __restrict__ Bm, int ldb,
                                                 const float* __restrict__ bias,
                                                 void* __restrict__ Cp, int ldc, int K) {
    constexpr int WM = BM / 2, WN = BN / 2;
    constexpr int MT = WM / 16, NT = WN / 16;
    __shared__ short As[BM * 32];
    __shared__ short Bs[BN * 32];

    const int tid = threadIdx.x;
    const int w = tid >> 6, l = tid & 63;
    const int wm = w >> 1, wn = w & 1;
    const int r0 = l & 15, q = l >> 4;
    const int m0 = blockIdx.y * BM, n0 = blockIdx.x * BN;

    // staging lane mapping: 16 rows x 4 segs per instruction (1 KB/wave-inst)
    const int lr = l >> 2, seg = l & 3;
    const int fseg = seg ^ ((lr >> 1) & 3);   // logical seg this lane fetches
    const int rkey = (r0 >> 1) & 3;           // read-side swizzle key

    const f32x4 zero4 = {0.f, 0.f, 0.f, 0.f};
    f32x4 acc[MT][NT];
#pragma unroll
    for (int mi = 0; mi < MT; ++mi)
#pragma unroll
        for (int ni = 0; ni < NT; ++ni) acc[mi][ni] = zero4;

    for (int k0 = 0; k0 < K; k0 += 32) {
        // async stage tile k0 (A: BM/64 chunks of 16 rows per wave; B likewise)
#pragma unroll
        for (int i = 0; i < BM / 64; ++i) {
            int rbase = w * (BM / 4) + i * 16;
            gld_lds16(A + (size_t)(m0 + rbase + lr) * lda + k0 + fseg * 8,
                      (char*)As + rbase * 64);
        }
#pragma unroll
        for (int i = 0; i < BN / 64; ++i) {
            int rbase = w * (BN / 4) + i * 16;
            gld_lds16(Bm + (size_t)(n0 + rbase + lr) * ldb + k0 + fseg * 8,
                      (char*)Bs + rbase * 64);
        }
        __syncthreads();   // drain vmcnt: tile k0 fully in LDS

        bf16x8 af[MT], bfr[NT];
#pragma unroll
        for (int mi = 0; mi < MT; ++mi)
            af[mi] = *(const bf16x8*)&As[(wm * WM + mi * 16 + r0) * 32 + (q ^ rkey) * 8];
#pragma unroll
        for (int ni = 0; ni < NT; ++ni)
            bfr[ni] = *(const bf16x8*)&Bs[(wn * WN + ni * 16 + r0) * 32 + (q ^ rkey) * 8];
#pragma unroll
        for (int mi = 0; mi < MT; ++mi)
#pragma unroll
            for (int ni = 0; ni < NT; ++ni)
                acc[mi][ni] = __builtin_amdgcn_mfma_f32_16x16x32_bf16(
                    af[mi], bfr[ni], acc[mi][ni], 0, 0, 0);
        __syncthreads();   // all reads done before next-iter overwrite
    }

    // epilogue: C/D layout col=lane&15, row=(lane>>4)*4+reg  [m89/m91]
#pragma unroll
    for (int mi = 0; mi < MT; ++mi) {
#pragma unroll
        for (int ni = 0; ni < NT; ++ni) {
            int col = n0 + wn * WN + ni * 16 + r0;
            float bb = bias[col];
#pragma unroll
            for (int r = 0; r < 4; ++r) {
                int row = m0 + wm * WM + mi * 16 + q * 4 + r;
                float v = acc[mi][ni][r] + bb;
                if (OUTBF) ((short*)Cp)[(size_t)row * ldc + col] = f2bf(v);
                else       ((float*)Cp)[(size_t)row * ldc + col] = v;
            }
        }
    }
}

// ---------------------------------------------------------------------------
// Interaction via MFMA: one wave per batch row. T = [dproj ; sparse] (27x128,
// zero-padded to 32). Gram = T.T^T with 16x16x32 MFMA; tril -> zfb[512:890] bf16,
// cols [890:896) zeroed. Skips the col>row tile (acc01 unused by tril).
// ---------------------------------------------------------------------------
__global__ __launch_bounds__(256) void interact_mfma(const float* __restrict__ sparse,
                                                     const short* __restrict__ dprojb,
                                                     short* __restrict__ zfb) {
    __shared__ short zt[4][NTRI];
    const int w = threadIdx.x >> 6, l = threadIdx.x & 63;
    const int b = blockIdx.x * 4 + w;
    const int r0 = l & 15, q = l >> 4;

    const float* srow = sparse + (size_t)b * (NSP * EMBD);
    const short* dp = dprojb + (size_t)b * EMBD;

    const f32x4 zero4 = {0.f, 0.f, 0.f, 0.f};
    f32x4 acc00 = zero4, acc10 = zero4, acc11 = zero4;

#pragma unroll
    for (int kc = 0; kc < 4; ++kc) {
        int k = kc * 32 + q * 8;
        bf16x8 f0, f1;
        if (r0 == 0) {
            f0 = *(const bf16x8*)(dp + k);                  // T row 0 = dense_proj
        } else {
            const float* p = srow + (size_t)(r0 - 1) * EMBD + k;
            f0 = cvt8(*(const float4*)p, *(const float4*)(p + 4));
        }
        if (r0 <= 10) {                                     // T rows 16..26
            const float* p = srow + (size_t)(15 + r0) * EMBD + k;
            f1 = cvt8(*(const float4*)p, *(const float4*)(p + 4));
        } else {
            f1 = (bf16x8){0, 0, 0, 0, 0, 0, 0, 0};
        }
        acc00 = __builtin_amdgcn_mfma_f32_16x16x32_bf16(f0, f0, acc00, 0, 0, 0);
        acc10 = __builtin_amdgcn_mfma_f32_16x16x32_bf16(f1, f0, acc10, 0, 0, 0);
        acc11 = __builtin_amdgcn_mfma_f32_16x16x32_bf16(f1, f1, acc11, 0, 0, 0);
    }

    // scatter tril entries to LDS: row=(mi*16 + q*4 + r), col=(ni*16 + r0)
#pragma unroll
    for (int r = 0; r < 4; ++r) {
        int row, col;
        row = q * 4 + r;       col = r0;                    // tile (0,0)
        if (col <= row)             zt[w][row * (row + 1) / 2 + col] = f2bf(acc00[r]);
        row = 16 + q * 4 + r;  col = r0;                    // tile (1,0)
        if (row < NI_)              zt[w][row * (row + 1) / 2 + col] = f2bf(acc10[r]);
        /* tile (1,1) */       col = 16 + r0;
        if (row < NI_ && col <= row) zt[w][row * (row + 1) / 2 + col] = f2bf(acc11[r]);
    }
    __syncthreads();

    // coalesced copy: 4 rows x (378 tril + 6 zero-pad) bf16
    const int b0 = blockIdx.x * 4;
    for (int idx = threadIdx.x; idx < 4 * 384; idx += 256) {
        int rw = idx / 384, c = idx - rw * 384;
        short v = (c < NTRI) ? zt[rw][c] : (short)0;
        zfb[(size_t)(b0 + rw) * KPAD + DIN + c] = v;
    }
}

// ---------------------------------------------------------------------------
extern "C" void kernel_launch(void* const* d_in, const int* in_sizes, int n_in,
                              void* d_out, int out_size, void* d_ws, size_t ws_size,
                              hipStream_t stream) {
    const float* dense  = (const float*)d_in[0];  // (16384, 512)
    const float* sparse = (const float*)d_in[1];  // (16384, 26, 128)
    const float* Wp     = (const float*)d_in[2];  // (128, 512)
    const float* bp     = (const float*)d_in[3];  // (128,)
    const float* Wo     = (const float*)d_in[4];  // (512, 890)
    const float* bo     = (const float*)d_in[5];  // (512,)
    float* out = (float*)d_out;                   // (16384, 512)

    short* zfb    = (short*)d_ws;                          // NB x 896 bf16
    short* dprojb = zfb + (size_t)NB * KPAD;               // NB x 128 bf16
    short* wop    = dprojb + (size_t)NB * EMBD;            // 512 x 896 bf16
    short* wpb    = wop + (size_t)NOUT * KPAD;             // 128 x 512 bf16

    // 1) weights -> bf16 (Wo padded)
    prep_w_k<<<(NOUT * KPAD + EMBD * DIN + 255) / 256, 256, 0, stream>>>(Wo, Wp, wop, wpb);

    // 2) dense -> bf16 into zfb[:, 0:512]
    conv_dense_k<<<(NB * 128 + 255) / 256, 256, 0, stream>>>(dense, zfb);

    // 3) dproj = dense @ Wp.T + bp  (M=16384, N=128, K=512), bf16 out
    gemm_mfma<128, 64, true><<<dim3(EMBD / 64, NB / 128), 256, 0, stream>>>(
        zfb, KPAD, wpb, DIN, bp, dprojb, EMBD, DIN);

    // 4) per-row Gram -> zfb[:, 512:896]
    interact_mfma<<<NB / 4, 256, 0, stream>>>(sparse, dprojb, zfb);

    // 5) out = Zflat @ Wo.T + bo  (M=16384, N=512, K=896), fp32 out
    gemm_mfma<128, 128, false><<<dim3(NOUT / 128, NB / 128), 256, 0, stream>>>(
        zfb, KPAD, wop, KPAD, bo, out, NOUT, KPAD);
}

// Round 4
// 375.901 us; speedup vs baseline: 1.5732x; 1.0198x over previous
//
#include <hip/hip_runtime.h>

// Problem constants
#define NB    16384   // batch
#define DIN   512     // dense in
#define NSP   26      // sparse embeddings
#define EMBD  128     // embedding dim
#define NOUT  512     // output dim
#define NI_   27      // NSP + 1
#define NTRI  378     // NI*(NI+1)/2
#define DOTK  890     // NTRI + DIN
#define KPAD  896     // DOTK padded to multiple of 64

typedef __attribute__((ext_vector_type(8)))  short bf16x8;  // 8 bf16 = 4 VGPRs
typedef __attribute__((ext_vector_type(4)))  float f32x4;   // MFMA 16x16 acc

// fp32 -> bf16 (RNE), bit-level
__device__ __forceinline__ short f2bf(float f) {
    unsigned u = __builtin_bit_cast(unsigned, f);
    unsigned r = (u + 0x7FFFu + ((u >> 16) & 1u)) >> 16;
    return (short)r;
}

__device__ __forceinline__ bf16x8 cvt8(float4 a, float4 b) {
    bf16x8 r;
    r[0] = f2bf(a.x); r[1] = f2bf(a.y); r[2] = f2bf(a.z); r[3] = f2bf(a.w);
    r[4] = f2bf(b.x); r[5] = f2bf(b.y); r[6] = f2bf(b.z); r[7] = f2bf(b.w);
    return r;
}

// async global -> LDS, 16 B per lane; lds dst is wave-uniform base (+lane*16 by HW)
__device__ __forceinline__ void gld_lds16(const void* g, void* l) {
    __builtin_amdgcn_global_load_lds((const __attribute__((address_space(1))) void*)g,
                                     (__attribute__((address_space(3))) void*)l,
                                     16, 0, 0);
}

// ---------------------------------------------------------------------------
// Merged prep: dense fp32 -> bf16 into zfb[:,0:512]; Wo -> bf16 padded (512x896);
// Wp -> bf16. All independent; one launch. ws re-poisoned each call -> must rerun.
// ---------------------------------------------------------------------------
#define CONV_N   (NB * 128)          // float4 groups of dense
#define WOP_N    (NOUT * KPAD)
#define WPB_N    (EMBD * DIN)
__global__ __launch_bounds__(256) void prep_all_k(const float* __restrict__ dense,
                                                  const float* __restrict__ Wo,
                                                  const float* __restrict__ Wp,
                                                  short* __restrict__ zfb,
                                                  short* __restrict__ wop,
                                                  short* __restrict__ wpb) {
    int idx = blockIdx.x * 256 + threadIdx.x;
    if (idx < CONV_N) {
        int b = idx >> 7, c = (idx & 127) * 4;
        float4 v = *(const float4*)(dense + (size_t)b * DIN + c);
        unsigned lo = ((unsigned)(unsigned short)f2bf(v.y) << 16) | (unsigned short)f2bf(v.x);
        unsigned hi = ((unsigned)(unsigned short)f2bf(v.w) << 16) | (unsigned short)f2bf(v.z);
        int2 pk; pk.x = (int)lo; pk.y = (int)hi;
        *(int2*)(zfb + (size_t)b * KPAD + c) = pk;
    } else if (idx < CONV_N + WOP_N) {
        int j = idx - CONV_N;
        int o = j / KPAD, k = j - o * KPAD;
        wop[j] = (k < DOTK) ? f2bf(Wo[o * DOTK + k]) : (short)0;
    } else {
        int j = idx - CONV_N - WOP_N;
        if (j < WPB_N) wpb[j] = f2bf(Wp[j]);
    }
}

// ---------------------------------------------------------------------------
// bf16 NT-GEMM via MFMA 16x16x32, BK=64: C[MxN] = A[Mxlda].rows(B[Nxldb]) + bias
// Block: 256 threads = 4 waves (2x2), each wave (BM/2 x BN/2).
// Staging: global_load_lds width=16. LDS rows = 64 shorts (128B = 8 16B-segs),
// XOR swizzle: physical seg = logical seg ^ (row&7). DMA writes lane->lane*16
// (conflict-free by construction); b128 read phases of 8 lanes hit 8 distinct
// segs -> conflict-free. Requires M%BM==0, N%BN==0, K%64==0. grid=(N/BN, M/BM).
// ---------------------------------------------------------------------------
template <int BM, int BN, bool OUTBF>
__global__ __launch_bounds__(256) void gemm_mfma(const short* __restrict__ A, int lda,
                                                 const short* __restrict__ Bm, int ldb,
                                                 const float* __restrict__ bias,
                                                 void* __restrict__ Cp, int ldc, int K) {
    constexpr int WM = BM / 2, WN = BN / 2;
    constexpr int MT = WM / 16, NT = WN / 16;
    __shared__ short As[BM * 64];
    __shared__ short Bs[BN * 64];

    const int tid = threadIdx.x;
    const int w = tid >> 6, l = tid & 63;
    const int wm = w >> 1, wn = w & 1;
    const int r0 = l & 15, q = l >> 4;
    const int m0 = blockIdx.y * BM, n0 = blockIdx.x * BN;

    // staging lane mapping: 8 rows x 8 segs per wave-instruction (1 KB)
    const int lr = l >> 3, pseg = l & 7;

    const f32x4 zero4 = {0.f, 0.f, 0.f, 0.f};
    f32x4 acc[MT][NT];
#pragma unroll
    for (int mi = 0; mi < MT; ++mi)
#pragma unroll
        for (int ni = 0; ni < NT; ++ni) acc[mi][ni] = zero4;

    for (int k0 = 0; k0 < K; k0 += 64) {
        // stage tile: wave w covers rows [w*(BM/4), ...), 8 rows per inst
#pragma unroll
        for (int i = 0; i < BM / 32; ++i) {
            int r = w * (BM / 4) + i * 8 + lr;           // global tile row
            int ls = pseg ^ (r & 7);                     // logical seg to fetch
            gld_lds16(A + (size_t)(m0 + r) * lda + k0 + ls * 8,
                      (char*)As + (w * (BM / 4) + i * 8) * 128);
        }
#pragma unroll
        for (int i = 0; i < BN / 32; ++i) {
            int r = w * (BN / 4) + i * 8 + lr;
            int ls = pseg ^ (r & 7);
            gld_lds16(Bm + (size_t)(n0 + r) * ldb + k0 + ls * 8,
                      (char*)Bs + (w * (BN / 4) + i * 8) * 128);
        }
        __syncthreads();   // vmcnt drain: tile fully in LDS

#pragma unroll
        for (int h = 0; h < 2; ++h) {                    // two K=32 halves
            bf16x8 af[MT], bfr[NT];
#pragma unroll
            for (int mi = 0; mi < MT; ++mi) {
                int r = wm * WM + mi * 16 + r0;
                af[mi] = *(const bf16x8*)&As[r * 64 + ((h * 4 + q) ^ (r & 7)) * 8];
            }
#pragma unroll
            for (int ni = 0; ni < NT; ++ni) {
                int r = wn * WN + ni * 16 + r0;
                bfr[ni] = *(const bf16x8*)&Bs[r * 64 + ((h * 4 + q) ^ (r & 7)) * 8];
            }
#pragma unroll
            for (int mi = 0; mi < MT; ++mi)
#pragma unroll
                for (int ni = 0; ni < NT; ++ni)
                    acc[mi][ni] = __builtin_amdgcn_mfma_f32_16x16x32_bf16(
                        af[mi], bfr[ni], acc[mi][ni], 0, 0, 0);
        }
        __syncthreads();   // all reads done before next-iter overwrite
    }

    // epilogue: C/D layout col=lane&15, row=(lane>>4)*4+reg  [m89/m91]
#pragma unroll
    for (int mi = 0; mi < MT; ++mi) {
#pragma unroll
        for (int ni = 0; ni < NT; ++ni) {
            int col = n0 + wn * WN + ni * 16 + r0;
            float bb = bias[col];
#pragma unroll
            for (int r = 0; r < 4; ++r) {
                int row = m0 + wm * WM + mi * 16 + q * 4 + r;
                float v = acc[mi][ni][r] + bb;
                if (OUTBF) ((short*)Cp)[(size_t)row * ldc + col] = f2bf(v);
                else       ((float*)Cp)[(size_t)row * ldc + col] = v;
            }
        }
    }
}

// ---------------------------------------------------------------------------
// Interaction via MFMA: one wave per batch row. T = [dproj ; sparse] (27x128,
// zero-padded to 32). Gram = T.T^T with 16x16x32 MFMA; tril -> zfb[512:890] bf16,
// cols [890:896) zeroed. Skips the col>row tile.
// ---------------------------------------------------------------------------
__global__ __launch_bounds__(256) void interact_mfma(const float* __restrict__ sparse,
                                                     const short* __restrict__ dprojb,
                                                     short* __restrict__ zfb) {
    __shared__ short zt[4][NTRI];
    const int w = threadIdx.x >> 6, l = threadIdx.x & 63;
    const int b = blockIdx.x * 4 + w;
    const int r0 = l & 15, q = l >> 4;

    const float* srow = sparse + (size_t)b * (NSP * EMBD);
    const short* dp = dprojb + (size_t)b * EMBD;

    const f32x4 zero4 = {0.f, 0.f, 0.f, 0.f};
    f32x4 acc00 = zero4, acc10 = zero4, acc11 = zero4;

#pragma unroll
    for (int kc = 0; kc < 4; ++kc) {
        int k = kc * 32 + q * 8;
        bf16x8 f0, f1;
        if (r0 == 0) {
            f0 = *(const bf16x8*)(dp + k);                  // T row 0 = dense_proj
        } else {
            const float* p = srow + (size_t)(r0 - 1) * EMBD + k;
            f0 = cvt8(*(const float4*)p, *(const float4*)(p + 4));
        }
        if (r0 <= 10) {                                     // T rows 16..26
            const float* p = srow + (size_t)(15 + r0) * EMBD + k;
            f1 = cvt8(*(const float4*)p, *(const float4*)(p + 4));
        } else {
            f1 = (bf16x8){0, 0, 0, 0, 0, 0, 0, 0};
        }
        acc00 = __builtin_amdgcn_mfma_f32_16x16x32_bf16(f0, f0, acc00, 0, 0, 0);
        acc10 = __builtin_amdgcn_mfma_f32_16x16x32_bf16(f1, f0, acc10, 0, 0, 0);
        acc11 = __builtin_amdgcn_mfma_f32_16x16x32_bf16(f1, f1, acc11, 0, 0, 0);
    }

    // scatter tril entries to LDS: row=(tile*16 + q*4 + r), col=(tile*16 + r0)
#pragma unroll
    for (int r = 0; r < 4; ++r) {
        int row, col;
        row = q * 4 + r;       col = r0;                    // tile (0,0)
        if (col <= row)             zt[w][row * (row + 1) / 2 + col] = f2bf(acc00[r]);
        row = 16 + q * 4 + r;  col = r0;                    // tile (1,0)
        if (row < NI_)              zt[w][row * (row + 1) / 2 + col] = f2bf(acc10[r]);
        /* tile (1,1) */       col = 16 + r0;
        if (row < NI_ && col <= row) zt[w][row * (row + 1) / 2 + col] = f2bf(acc11[r]);
    }
    __syncthreads();

    // coalesced copy: 4 rows x (378 tril + 6 zero-pad) bf16
    const int b0 = blockIdx.x * 4;
    for (int idx = threadIdx.x; idx < 4 * 384; idx += 256) {
        int rw = idx / 384, c = idx - rw * 384;
        short v = (c < NTRI) ? zt[rw][c] : (short)0;
        zfb[(size_t)(b0 + rw) * KPAD + DIN + c] = v;
    }
}

// ---------------------------------------------------------------------------
extern "C" void kernel_launch(void* const* d_in, const int* in_sizes, int n_in,
                              void* d_out, int out_size, void* d_ws, size_t ws_size,
                              hipStream_t stream) {
    const float* dense  = (const float*)d_in[0];  // (16384, 512)
    const float* sparse = (const float*)d_in[1];  // (16384, 26, 128)
    const float* Wp     = (const float*)d_in[2];  // (128, 512)
    const float* bp     = (const float*)d_in[3];  // (128,)
    const float* Wo     = (const float*)d_in[4];  // (512, 890)
    const float* bo     = (const float*)d_in[5];  // (512,)
    float* out = (float*)d_out;                   // (16384, 512)

    short* zfb    = (short*)d_ws;                          // NB x 896 bf16
    short* dprojb = zfb + (size_t)NB * KPAD;               // NB x 128 bf16
    short* wop    = dprojb + (size_t)NB * EMBD;            // 512 x 896 bf16
    short* wpb    = wop + (size_t)NOUT * KPAD;             // 128 x 512 bf16

    // 1) all conversions in one launch
    prep_all_k<<<(CONV_N + WOP_N + WPB_N + 255) / 256, 256, 0, stream>>>(
        dense, Wo, Wp, zfb, wop, wpb);

    // 2) dproj = dense @ Wp.T + bp  (M=16384, N=128, K=512), bf16 out
    gemm_mfma<128, 64, true><<<dim3(EMBD / 64, NB / 128), 256, 0, stream>>>(
        zfb, KPAD, wpb, DIN, bp, dprojb, EMBD, DIN);

    // 3) per-row Gram -> zfb[:, 512:896]
    interact_mfma<<<NB / 4, 256, 0, stream>>>(sparse, dprojb, zfb);

    // 4) out = Zflat @ Wo.T + bo  (M=16384, N=512, K=896), fp32 out
    gemm_mfma<128, 128, false><<<dim3(NOUT / 128, NB / 128), 256, 0, stream>>>(
        zfb, KPAD, wop, KPAD, bo, out, NOUT, KPAD);
}